// Round 7
// baseline (167.242 us; speedup 1.0000x reference)
//
#include <hip/hip_runtime.h>
#include <stdint.h>

#define SAMPLES   524288
#define BATCH     16
#define T_FRAMES  2048
#define HOPSZ     256
#define NCH       513
#define KF        512            // folded K (DFT cols 1..512)
#define MF        1152           // folded M: 36 groups of {16 cos | 16 sin}
#define HALF_FR   16384          // frames per half-pass (8 batches)

// workspace layout (total 33.1 MiB < proven 35.8 MiB footprint)
#define SB_OFF    1183744        // after Wf (1152*512*2 = 1.13 MiB, 4K-aligned)
#define DB_OFF    17960960       // after Sb (16.78 MiB)

typedef __bf16          bf16x8 __attribute__((ext_vector_type(8)));
typedef float           f32x4  __attribute__((ext_vector_type(4)));
typedef unsigned short  u16x8  __attribute__((ext_vector_type(8)));

__device__ __forceinline__ unsigned short f2bf(float f) {
    union { float f; unsigned u; } v; v.f = f;
    unsigned r = v.u + 0x7fffu + ((v.u >> 16) & 1u);   // round-to-nearest-even
    return (unsigned short)(r >> 16);
}

// ---------- prep: weight fold-gather + s/d fold ---------------------------
// Fold identity (exact): win symmetric, win[0]=0 ->
//   re_k = sum_{n=0..511} Wf_s[k,n] * s_t[n],  s_t[n] = x_t[n+1]+x_t[1023-n]
//   im_k = sum_{n=0..511} Wf_d[k,n] * d_t[n],  d_t[n] = x_t[n+1]-x_t[1023-n]
// col 511 is the n=512 self-pair: s=2*x_t[512] -> cos weight halved; sin
// weight there is exactly 0 (sin(pi k)=0), d=0. M layout: group g has
// {16 cos rows bins g*16+r | 16 sin rows}; invalid rows (cos bin>512,
// sin bin 0 or >511) are zero -> bin-0/512 magnitudes need no special case.
// half==0: blocks [0,288) gather weights, [288,288+4096) fold batches 0-7.
// half==1: 4096 blocks fold batches 8-15.
__global__ void prep(const float* __restrict__ x, const float* __restrict__ wsrc,
                     unsigned short* __restrict__ Wf,
                     unsigned short* __restrict__ Sb,
                     unsigned short* __restrict__ Db, int half) {
    int bid = blockIdx.x;
    const int tid = threadIdx.x;
    if (half == 0) {
        if (bid < 288) {                       // weight gather: 1152 x 512
            int gid = bid * 256 + tid;         // 8 u16 each
            int m   = gid >> 6;
            int n0  = (gid & 63) << 3;
            int g = m >> 5, h = (m >> 4) & 1, r = m & 15;
            int bin = g * 16 + r;
            bool valid = h ? (bin >= 1 && bin <= 511) : (bin <= 512);
            const float* ws = wsrc + (long long)(h ? NCH + bin : bin) * 1024;
            union { u16x8 v; unsigned short e[8]; } o;
            #pragma unroll
            for (int e = 0; e < 8; ++e) {
                int n = n0 + e;
                float v = 0.f;
                if (valid) v = (n < 511) ? ws[n + 1] : 0.5f * ws[512];
                o.e[e] = f2bf(v);
            }
            *(u16x8*)(Wf + (long long)m * KF + n0) = o.v;
            return;
        }
        bid -= 288;
    }
    // ---- s/d fold: 4 frames per block, 64 threads per frame (8 cols each)
    const int fr = tid >> 6;
    const int n0 = (tid & 63) << 3;
    const long long f = (long long)bid * 4 + fr;     // frame within half
    const int bat = half * 8 + (int)(f >> 11);
    const int t   = (int)(f & 2047);
    const float* xb = x + (long long)bat * SAMPLES;
    float fwd[8], rev[8];
    if (t >= 4) {       // fast path: no pad in window; aligned f32x4 loads
        // fwd[e] = x[t*256 + n0 + e - 1022]; aligned base offset -1024
        const f32x4* pf = (const f32x4*)(xb + (t * 256 + n0 - 1024));
        f32x4 A = pf[0], B = pf[1], C = pf[2];
        fwd[0]=A[2]; fwd[1]=A[3]; fwd[2]=B[0]; fwd[3]=B[1];
        fwd[4]=B[2]; fwd[5]=B[3]; fwd[6]=C[0]; fwd[7]=C[1];
        // rev[e] = x[t*256 - n0 - e]; ascending run base offset -n0-8
        const f32x4* pr = (const f32x4*)(xb + (t * 256 - n0 - 8));
        f32x4 D = pr[0], E = pr[1], F = pr[2];
        rev[0]=F[0]; rev[1]=E[3]; rev[2]=E[2]; rev[3]=E[1];
        rev[4]=E[0]; rev[5]=D[3]; rev[6]=D[2]; rev[7]=D[1];
    } else {            // first 4 frames of each batch touch the zero pad
        #pragma unroll
        for (int e = 0; e < 8; ++e) {
            int n  = n0 + e;
            int pf = t * 256 + n + 1 - 1023;
            int pr = t * 256 - n;
            fwd[e] = (pf >= 0) ? xb[pf] : 0.f;
            rev[e] = (pr >= 0) ? xb[pr] : 0.f;
        }
    }
    union { u16x8 v; unsigned short e[8]; } so, dof;
    #pragma unroll
    for (int e = 0; e < 8; ++e) {
        so.e[e]  = f2bf(fwd[e] + rev[e]);
        dof.e[e] = f2bf(fwd[e] - rev[e]);
    }
    *(u16x8*)(Sb + f * KF + n0) = so.v;
    *(u16x8*)(Db + f * KF + n0) = dof.v;
}

// ---------- async global -> LDS (16 B/lane, dst = wave-uniform base + lane*16)
__device__ __forceinline__ void gll16(const unsigned short* g, unsigned short* s) {
    __builtin_amdgcn_global_load_lds(
        (const __attribute__((address_space(1))) void*)g,
        (__attribute__((address_space(3))) void*)s,
        16, 0, 0);
}

// ---------- folded GEMM + magnitude epilogue ------------------------------
// r2's proven TLP structure (2-barrier 128x128 tile, 16x16x32 MFMA, 0 bank
// conflicts) with K=512 fold: A-frags alternate {s-rows, d-rows} per 16, so
// even frags multiply the s-tile, odd frags the d-tile. LDS 48 KB -> still
// 3 blocks/CU. Grid 1152 = 9 M-tiles x 128 frame-tiles (one 8-batch half);
// XCD stripe: each XCD owns exactly one batch's s/d slice (~4.2 MB).
__global__ __launch_bounds__(256, 3)
void stft_gemm(const unsigned short* __restrict__ Sb,
               const unsigned short* __restrict__ Db,
               const unsigned short* __restrict__ Wf,
               float* __restrict__ out, int half) {
    __shared__ unsigned short Ws[128 * 64];   // 16 KB
    __shared__ unsigned short Ss[128 * 64];   // 16 KB
    __shared__ unsigned short Ds[128 * 64];   // 16 KB

    const int id  = blockIdx.x;               // 1152
    const int xcd = id & 7;
    const int idx = id >> 3;                  // 0..143
    const int nt  = idx >> 4;                 // 0..8  M tile
    const int ft  = (xcd << 4) | (idx & 15);  // 0..127 frame tile
    const int bh  = ft >> 4;                  // batch within half (== xcd)
    const int t0  = (ft & 15) * 128;
    const long long fl0 = (long long)bh * 2048 + t0;

    const int tid = threadIdx.x;
    const int l   = tid & 63;
    const int w   = tid >> 6;
    const int ln  = l & 15;
    const int qd  = l >> 4;

    // staging: wave w stages rows [w*32, w*32+32) of each tile, 4 gll16 per
    // tile; call c: row = w*32 + c*8 + (l>>3), lds chunk = l&7 (implicit),
    // global chunk = (l&7) ^ (row&7).
    const int srow   = l >> 3;
    const int schunk = l & 7;

    const unsigned short* asrc[4];
    const unsigned short* ssrc[4];
    const unsigned short* dsrc[4];
    unsigned short* adst[4];
    unsigned short* sdst[4];
    unsigned short* ddst[4];
    #pragma unroll
    for (int c = 0; c < 4; ++c) {
        int r = w * 32 + c * 8 + srow;
        int gchunk = schunk ^ (r & 7);
        asrc[c] = Wf + (long long)(nt * 128 + r) * KF + gchunk * 8;
        ssrc[c] = Sb + (fl0 + r) * KF + gchunk * 8;
        dsrc[c] = Db + (fl0 + r) * KF + gchunk * 8;
        adst[c] = Ws + (w * 32 + c * 8) * 64;
        sdst[c] = Ss + (w * 32 + c * 8) * 64;
        ddst[c] = Ds + (w * 32 + c * 8) * 64;
    }

    const int wave_m = w & 1;
    const int wave_n = w >> 1;

    f32x4 acc[4][4];
    #pragma unroll
    for (int i = 0; i < 4; ++i)
        #pragma unroll
        for (int j = 0; j < 4; ++j)
            acc[i][j] = (f32x4){0.f, 0.f, 0.f, 0.f};

    // ds_read offsets (identical pattern to the 0-conflict r2 kernel)
    int a_off[4][2], b_off[4][2];
    #pragma unroll
    for (int i = 0; i < 4; ++i)
        #pragma unroll
        for (int k2 = 0; k2 < 2; ++k2) {
            int ck = ((k2 * 4 + qd) ^ (ln & 7)) * 8;
            a_off[i][k2] = (wave_m * 64 + i * 16 + ln) * 64 + ck;
            b_off[i][k2] = (wave_n * 64 + i * 16 + ln) * 64 + ck;
        }

    for (int kk = 0; kk < KF; kk += 64) {     // 8 K-steps
        #pragma unroll
        for (int c = 0; c < 4; ++c) gll16(asrc[c] + kk, adst[c]);
        #pragma unroll
        for (int c = 0; c < 4; ++c) gll16(ssrc[c] + kk, sdst[c]);
        #pragma unroll
        for (int c = 0; c < 4; ++c) gll16(dsrc[c] + kk, ddst[c]);
        __syncthreads();

        #pragma unroll
        for (int k2 = 0; k2 < 2; ++k2) {
            bf16x8 av[4], bs[4], bd[4];
            #pragma unroll
            for (int i = 0; i < 4; ++i) av[i] = *(const bf16x8*)&Ws[a_off[i][k2]];
            #pragma unroll
            for (int j = 0; j < 4; ++j) bs[j] = *(const bf16x8*)&Ss[b_off[j][k2]];
            #pragma unroll
            for (int j = 0; j < 4; ++j) bd[j] = *(const bf16x8*)&Ds[b_off[j][k2]];
            #pragma unroll
            for (int j = 0; j < 4; ++j) {
                acc[0][j] = __builtin_amdgcn_mfma_f32_16x16x32_bf16(av[0], bs[j], acc[0][j], 0, 0, 0);
                acc[1][j] = __builtin_amdgcn_mfma_f32_16x16x32_bf16(av[1], bd[j], acc[1][j], 0, 0, 0);
                acc[2][j] = __builtin_amdgcn_mfma_f32_16x16x32_bf16(av[2], bs[j], acc[2][j], 0, 0, 0);
                acc[3][j] = __builtin_amdgcn_mfma_f32_16x16x32_bf16(av[3], bd[j], acc[3][j], 0, 0, 0);
            }
        }
        __syncthreads();
    }

    // ---- epilogue: frag pair (2p, 2p+1) = (s=re, d=im) of bin group
    // q = nt*4 + wave_m*2 + p; bin = q*16 + qd*4 + r. Zero-weight rows make
    // im(bin0)=im(bin512)=0 automatically; pad bins guarded by bin<NCH.
    const int b = half * 8 + bh;
    float* outb = out + (long long)b * (NCH * T_FRAMES);
    #pragma unroll
    for (int p = 0; p < 2; ++p) {
        #pragma unroll
        for (int j = 0; j < 4; ++j) {
            const int t = t0 + wave_n * 64 + j * 16 + ln;
            #pragma unroll
            for (int r = 0; r < 4; ++r) {
                float re  = acc[2 * p][j][r];
                float im  = acc[2 * p + 1][j][r];
                int bin = (nt * 4 + wave_m * 2 + p) * 16 + qd * 4 + r;
                if (bin < NCH)
                    outb[(long long)bin * T_FRAMES + t] =
                        sqrtf(fmaxf(re * re + im * im, 1e-12f));
            }
        }
    }
}

extern "C" void kernel_launch(void* const* d_in, const int* in_sizes, int n_in,
                              void* d_out, int out_size, void* d_ws, size_t ws_size,
                              hipStream_t stream) {
    const float* x  = (const float*)d_in[0];
    const float* wt = (const float*)d_in[1];
    float* out = (float*)d_out;

    unsigned short* Wf = (unsigned short*)d_ws;                       // 1.13 MiB
    unsigned short* Sb = (unsigned short*)((char*)d_ws + SB_OFF);     // 16.78 MiB
    unsigned short* Db = (unsigned short*)((char*)d_ws + DB_OFF);     // 16.78 MiB

    prep<<<4384, 256, 0, stream>>>(x, wt, Wf, Sb, Db, 0);  // weights + fold b0-7
    stft_gemm<<<1152, 256, 0, stream>>>(Sb, Db, Wf, out, 0);
    prep<<<4096, 256, 0, stream>>>(x, wt, Wf, Sb, Db, 1);  // fold b8-15
    stft_gemm<<<1152, 256, 0, stream>>>(Sb, Db, Wf, out, 1);
}